// Round 6
// baseline (928.120 us; speedup 1.0000x reference)
//
#include <hip/hip_runtime.h>
#include <hip/hip_bf16.h>
#include <hip/hip_fp16.h>

// Problem constants (fixed by the reference)
#define NN 50000
#define EE 800000
#define CC 128
#define HH 2
#define ATT_SLOPE 0.2f
#define OUT_SLOPE 0.01f

__device__ __forceinline__ float lrelu(float v, float s) {
    return v > 0.0f ? v : s * v;
}

// load 4 consecutive fp16 and widen to float4 (8B per lane)
__device__ __forceinline__ float4 ld_half4(const __half* p) {
    uint2 u = *(const uint2*)p;
    float2 fa = __half22float2(*reinterpret_cast<const __half2*>(&u.x));
    float2 fb = __half22float2(*reinterpret_cast<const __half2*>(&u.y));
    return make_float4(fa.x, fa.y, fb.x, fb.y);
}

// ---------------- CSR build ----------------

__global__ void zero_kernel(int* __restrict__ p, int n) {
    int i = blockIdx.x * blockDim.x + threadIdx.x;
    if (i < n) p[i] = 0;
}

__global__ void count_kernel(const int* __restrict__ dst, int* __restrict__ cnt,
                             int E, int N) {
    int i = blockIdx.x * blockDim.x + threadIdx.x;
    int total = E + N;
    if (i >= total) return;
    int d = (i < E) ? dst[i] : (i - E);   // self loops appended
    atomicAdd(&cnt[d], 1);
}

// hierarchical scan, 3 kernels
__global__ __launch_bounds__(256) void bsum_kernel(const int* __restrict__ cnt,
                                                   int* __restrict__ bsum, int n) {
    __shared__ int sh[4];
    int i = blockIdx.x * 256 + threadIdx.x;
    int v = (i < n) ? cnt[i] : 0;
    #pragma unroll
    for (int off = 32; off; off >>= 1) v += __shfl_xor(v, off);
    if ((threadIdx.x & 63) == 0) sh[threadIdx.x >> 6] = v;
    __syncthreads();
    if (threadIdx.x == 0) bsum[blockIdx.x] = sh[0] + sh[1] + sh[2] + sh[3];
}

__global__ __launch_bounds__(256) void bscan_kernel(int* __restrict__ bsum, int nb) {
    __shared__ int buf[2][256];
    int t = threadIdx.x;
    int v = (t < nb) ? bsum[t] : 0;
    buf[0][t] = v;
    __syncthreads();
    int cur = 0;
    for (int off = 1; off < 256; off <<= 1) {
        int nxt = cur ^ 1;
        int add = (t >= off) ? buf[cur][t - off] : 0;
        buf[nxt][t] = buf[cur][t] + add;
        __syncthreads();
        cur = nxt;
    }
    if (t < nb) bsum[t] = buf[cur][t] - v;  // exclusive
}

__global__ __launch_bounds__(256) void scan2_kernel(const int* __restrict__ cnt,
                                                    const int* __restrict__ boff,
                                                    int* __restrict__ rowptr,
                                                    int* __restrict__ fillptr, int n) {
    __shared__ int buf[2][256];
    int t = threadIdx.x;
    int i = blockIdx.x * 256 + t;
    int v = (i < n) ? cnt[i] : 0;
    buf[0][t] = v;
    __syncthreads();
    int cur = 0;
    for (int off = 1; off < 256; off <<= 1) {
        int nxt = cur ^ 1;
        int add = (t >= off) ? buf[cur][t - off] : 0;
        buf[nxt][t] = buf[cur][t] + add;
        __syncthreads();
        cur = nxt;
    }
    int excl = buf[cur][t] - v + boff[blockIdx.x];
    if (i < n) { rowptr[i] = excl; fillptr[i] = excl; }
    if (i == n - 1) rowptr[n] = excl + v;
}

// scatter also records the original edge id (or -1 for self-loops) so the
// score kernel can walk edges in dst-grouped (CSR) order.
__global__ void scatter_kernel(const int* __restrict__ src, const int* __restrict__ dst,
                               int* __restrict__ fillptr, int* __restrict__ col,
                               int* __restrict__ eid, int E, int N) {
    int i = blockIdx.x * blockDim.x + threadIdx.x;
    int total = E + N;
    if (i >= total) return;
    int s, d, e;
    if (i < E) { s = src[i]; d = dst[i]; e = i; }
    else       { s = d = i - E; e = -1; }
    int pos = atomicAdd(&fillptr[d], 1);
    col[pos] = s;
    eid[pos] = e;
}

// ---------------- GEMM: xp[n, 0:256] = X[n,:] @ W  (+ fused a4 dots) ----------------
// 128x128 block tile (blockIdx.y = head), 8x8 register tile, BK=32.
// XP stored as fp16 (gather table for agg) -- a4 dots computed from fp32 accs,
// so attention logits stay exact; only message values carry ~4.9e-4 rel error.

#define BM 128
#define BK 32

#define FMA8(i, ac, bb0, bb1) \
    acc[i][0] += ac * bb0.x; acc[i][1] += ac * bb0.y; acc[i][2] += ac * bb0.z; acc[i][3] += ac * bb0.w; \
    acc[i][4] += ac * bb1.x; acc[i][5] += ac * bb1.y; acc[i][6] += ac * bb1.z; acc[i][7] += ac * bb1.w;

__global__ __launch_bounds__(256) void gemm_kernel(const float* __restrict__ X,
                            const float* __restrict__ W,
                            const float* __restrict__ a_src,
                            const float* __restrict__ a_dst,
                            __half* __restrict__ XP,
                            float* __restrict__ a4,
                            int M) {
    __shared__ float As[BM][BK + 4];     // stride 36 words
    __shared__ float Bs[BK][128 + 4];    // stride 132 words
    int m0 = blockIdx.x * BM;
    int h  = blockIdx.y;                 // head: cols h*128 .. h*128+127
    int n0 = h << 7;
    int t  = threadIdx.x;
    int tx = t & 15;                     // cols tx*8 .. tx*8+7 (within head)
    int ty = t >> 4;                     // rows ty*8 .. ty*8+7

    float acc[8][8] = {};

    for (int kt = 0; kt < CC; kt += BK) {
        // fill As: 128x32 floats = 1024 float4, 4 per thread
        #pragma unroll
        for (int j = 0; j < 4; ++j) {
            int idx = t + j * 256;
            int row = idx >> 3;
            int kq  = idx & 7;
            float4 v = make_float4(0.f, 0.f, 0.f, 0.f);
            if (m0 + row < M)
                v = *(const float4*)(X + (size_t)(m0 + row) * CC + kt + kq * 4);
            *(float4*)(&As[row][kq * 4]) = v;
        }
        // fill Bs: 32x128 floats = 1024 float4, 4 per thread
        #pragma unroll
        for (int j = 0; j < 4; ++j) {
            int idx = t + j * 256;
            int k   = idx >> 5;
            int cq  = idx & 31;
            *(float4*)(&Bs[k][cq * 4]) =
                *(const float4*)(W + (size_t)(kt + k) * 256 + n0 + cq * 4);
        }
        __syncthreads();
        #pragma unroll
        for (int k0 = 0; k0 < BK; k0 += 4) {
            float4 av[8];
            #pragma unroll
            for (int i = 0; i < 8; ++i)
                av[i] = *(const float4*)(&As[ty * 8 + i][k0]);
            #pragma unroll
            for (int kk = 0; kk < 4; ++kk) {
                float4 b0 = *(const float4*)(&Bs[k0 + kk][tx * 8]);
                float4 b1 = *(const float4*)(&Bs[k0 + kk][tx * 8 + 4]);
                if (kk == 0) { FMA8(0, av[0].x, b0, b1); FMA8(1, av[1].x, b0, b1); FMA8(2, av[2].x, b0, b1); FMA8(3, av[3].x, b0, b1); FMA8(4, av[4].x, b0, b1); FMA8(5, av[5].x, b0, b1); FMA8(6, av[6].x, b0, b1); FMA8(7, av[7].x, b0, b1); }
                if (kk == 1) { FMA8(0, av[0].y, b0, b1); FMA8(1, av[1].y, b0, b1); FMA8(2, av[2].y, b0, b1); FMA8(3, av[3].y, b0, b1); FMA8(4, av[4].y, b0, b1); FMA8(5, av[5].y, b0, b1); FMA8(6, av[6].y, b0, b1); FMA8(7, av[7].y, b0, b1); }
                if (kk == 2) { FMA8(0, av[0].z, b0, b1); FMA8(1, av[1].z, b0, b1); FMA8(2, av[2].z, b0, b1); FMA8(3, av[3].z, b0, b1); FMA8(4, av[4].z, b0, b1); FMA8(5, av[5].z, b0, b1); FMA8(6, av[6].z, b0, b1); FMA8(7, av[7].z, b0, b1); }
                if (kk == 3) { FMA8(0, av[0].w, b0, b1); FMA8(1, av[1].w, b0, b1); FMA8(2, av[2].w, b0, b1); FMA8(3, av[3].w, b0, b1); FMA8(4, av[4].w, b0, b1); FMA8(5, av[5].w, b0, b1); FMA8(6, av[6].w, b0, b1); FMA8(7, av[7].w, b0, b1); }
            }
        }
        __syncthreads();
    }

    // epilogue: fp16 XP store + fused a4 dots (full head per block -> plain store)
    int coff = tx * 8;
    float4 as0 = *(const float4*)(a_src + h * 128 + coff);
    float4 as1 = *(const float4*)(a_src + h * 128 + coff + 4);
    float4 ad0 = *(const float4*)(a_dst + h * 128 + coff);
    float4 ad1 = *(const float4*)(a_dst + h * 128 + coff + 4);
    #pragma unroll
    for (int i = 0; i < 8; ++i) {
        int row = m0 + ty * 8 + i;
        float ps = acc[i][0] * as0.x + acc[i][1] * as0.y + acc[i][2] * as0.z + acc[i][3] * as0.w
                 + acc[i][4] * as1.x + acc[i][5] * as1.y + acc[i][6] * as1.z + acc[i][7] * as1.w;
        float pd = acc[i][0] * ad0.x + acc[i][1] * ad0.y + acc[i][2] * ad0.z + acc[i][3] * ad0.w
                 + acc[i][4] * ad1.x + acc[i][5] * ad1.y + acc[i][6] * ad1.z + acc[i][7] * ad1.w;
        #pragma unroll
        for (int off = 1; off < 16; off <<= 1) {
            ps += __shfl_xor(ps, off);
            pd += __shfl_xor(pd, off);
        }
        if (row < M) {
            __half2 h0 = __floats2half2_rn(acc[i][0], acc[i][1]);
            __half2 h1 = __floats2half2_rn(acc[i][2], acc[i][3]);
            __half2 h2 = __floats2half2_rn(acc[i][4], acc[i][5]);
            __half2 h3 = __floats2half2_rn(acc[i][6], acc[i][7]);
            uint4 pack;
            pack.x = *reinterpret_cast<unsigned*>(&h0);
            pack.y = *reinterpret_cast<unsigned*>(&h1);
            pack.z = *reinterpret_cast<unsigned*>(&h2);
            pack.w = *reinterpret_cast<unsigned*>(&h3);
            *(uint4*)(XP + (size_t)row * 256 + n0 + tx * 8) = pack;
            if (tx == 0) {
                a4[(size_t)row * 4 + h]     = ps;
                a4[(size_t)row * 4 + 2 + h] = pd;
            }
        }
    }
}

// ---------------- CSR aggregation -------------------------------------------------
// One 32-lane HALF-WAVE per node (2 nodes/wave, 8/block): lanes q=0..15 head0,
// q=16..31 head1, 8 channels per lane via 16B uint4 gathers (half the load
// instructions of the 8B layout, 2 independent edge streams per wave).
// Max-free softmax (logits bounded), fp32 accumulate, post-act fp32 out,
// optional fp16 pre-act shadow for the score kernel.
__global__ __launch_bounds__(256) void agg_kernel(const __half* __restrict__ xp,
                           const float* __restrict__ a4,
                           const int* __restrict__ rowptr,
                           const int* __restrict__ col,
                           const float* __restrict__ bias,
                           float* __restrict__ out_post,
                           __half* __restrict__ shadow,
                           int write_shadow) {
    int tid = threadIdx.x;
    int n = blockIdx.x * 8 + (tid >> 5);
    int q = tid & 31;
    int h = q >> 4;                       // head
    int c8 = (q & 15) * 8;                // first of this lane's 8 channels
    int r0 = rowptr[n], r1 = rowptr[n + 1];
    float2 adv = *(const float2*)(a4 + (size_t)n * 4 + 2);   // dst.h0, dst.h1
    float ad = h ? adv.y : adv.x;

    float denom = 0.f;
    float acc[8] = {0.f, 0.f, 0.f, 0.f, 0.f, 0.f, 0.f, 0.f};

#define ACC8(u, xw) do { \
        float2 f0 = __half22float2(*reinterpret_cast<const __half2*>(&u.x)); \
        float2 f1 = __half22float2(*reinterpret_cast<const __half2*>(&u.y)); \
        float2 f2 = __half22float2(*reinterpret_cast<const __half2*>(&u.z)); \
        float2 f3 = __half22float2(*reinterpret_cast<const __half2*>(&u.w)); \
        acc[0] += xw * f0.x; acc[1] += xw * f0.y; \
        acc[2] += xw * f1.x; acc[3] += xw * f1.y; \
        acc[4] += xw * f2.x; acc[5] += xw * f2.y; \
        acc[6] += xw * f3.x; acc[7] += xw * f3.y; } while (0)

    int k = r0;
    for (; k + 3 < r1; k += 4) {
        int s0 = col[k], s1 = col[k + 1], s2 = col[k + 2], s3 = col[k + 3];
        float2 av0 = *(const float2*)(a4 + (size_t)s0 * 4);
        float2 av1 = *(const float2*)(a4 + (size_t)s1 * 4);
        float2 av2 = *(const float2*)(a4 + (size_t)s2 * 4);
        float2 av3 = *(const float2*)(a4 + (size_t)s3 * 4);
        uint4 u0 = *(const uint4*)(xp + (size_t)s0 * 256 + q * 8);
        uint4 u1 = *(const uint4*)(xp + (size_t)s1 * 256 + q * 8);
        uint4 u2 = *(const uint4*)(xp + (size_t)s2 * 256 + q * 8);
        uint4 u3 = *(const uint4*)(xp + (size_t)s3 * 256 + q * 8);
        float x0 = __expf(lrelu((h ? av0.y : av0.x) + ad, ATT_SLOPE));
        float x1 = __expf(lrelu((h ? av1.y : av1.x) + ad, ATT_SLOPE));
        float x2 = __expf(lrelu((h ? av2.y : av2.x) + ad, ATT_SLOPE));
        float x3 = __expf(lrelu((h ? av3.y : av3.x) + ad, ATT_SLOPE));
        denom += (x0 + x1) + (x2 + x3);
        ACC8(u0, x0); ACC8(u1, x1); ACC8(u2, x2); ACC8(u3, x3);
    }
    for (; k < r1; ++k) {
        int s0 = col[k];
        float2 av0 = *(const float2*)(a4 + (size_t)s0 * 4);
        uint4 u0 = *(const uint4*)(xp + (size_t)s0 * 256 + q * 8);
        float x0 = __expf(lrelu((h ? av0.y : av0.x) + ad, ATT_SLOPE));
        denom += x0;
        ACC8(u0, x0);
    }
#undef ACC8

    float inv = 1.0f / (denom + 1e-16f);
    float v[8], o[8];
    #pragma unroll
    for (int j = 0; j < 8; ++j) v[j] = acc[j] * inv;
    #pragma unroll
    for (int j = 0; j < 8; ++j) o[j] = __shfl_xor(v[j], 16);  // partner head, same ch
    if (h == 0) {
        float4 b0 = *(const float4*)(bias + c8);
        float4 b1 = *(const float4*)(bias + c8 + 4);
        float pre[8];
        pre[0] = 0.5f * (v[0] + o[0]) + b0.x;
        pre[1] = 0.5f * (v[1] + o[1]) + b0.y;
        pre[2] = 0.5f * (v[2] + o[2]) + b0.z;
        pre[3] = 0.5f * (v[3] + o[3]) + b0.w;
        pre[4] = 0.5f * (v[4] + o[4]) + b1.x;
        pre[5] = 0.5f * (v[5] + o[5]) + b1.y;
        pre[6] = 0.5f * (v[6] + o[6]) + b1.z;
        pre[7] = 0.5f * (v[7] + o[7]) + b1.w;
        float4 p0 = make_float4(lrelu(pre[0], OUT_SLOPE), lrelu(pre[1], OUT_SLOPE),
                                lrelu(pre[2], OUT_SLOPE), lrelu(pre[3], OUT_SLOPE));
        float4 p1 = make_float4(lrelu(pre[4], OUT_SLOPE), lrelu(pre[5], OUT_SLOPE),
                                lrelu(pre[6], OUT_SLOPE), lrelu(pre[7], OUT_SLOPE));
        *(float4*)(out_post + (size_t)n * CC + c8)     = p0;
        *(float4*)(out_post + (size_t)n * CC + c8 + 4) = p1;
        if (write_shadow) {
            __half2 s0 = __floats2half2_rn(pre[0], pre[1]);
            __half2 s1 = __floats2half2_rn(pre[2], pre[3]);
            __half2 s2 = __floats2half2_rn(pre[4], pre[5]);
            __half2 s3 = __floats2half2_rn(pre[6], pre[7]);
            uint4 pk;
            pk.x = *reinterpret_cast<unsigned*>(&s0);
            pk.y = *reinterpret_cast<unsigned*>(&s1);
            pk.z = *reinterpret_cast<unsigned*>(&s2);
            pk.w = *reinterpret_cast<unsigned*>(&s3);
            *(uint4*)(shadow + (size_t)n * CC + c8) = pk;
        }
    }
}

// ---------------- edge score, CSR (dst-grouped) order -----------------------------
// One 32-lane half-wave per dst node: xq[dst] loaded ONCE per node instead of per
// edge (row-gathers 1.6M -> 850k). eid<0 marks self-loop slots (no score).
__global__ __launch_bounds__(256) void score_kernel(const __half* __restrict__ xq,
                             const int* __restrict__ rowptr,
                             const int* __restrict__ col,
                             const int* __restrict__ eid,
                             const float* __restrict__ ea,
                             float* __restrict__ score) {
    int tid = threadIdx.x;
    int n = blockIdx.x * 8 + (tid >> 5);
    int q = tid & 31;
    int r0 = rowptr[n], r1 = rowptr[n + 1];
    float4 xd = ld_half4(xq + (size_t)n * CC + q * 4);

    int k = r0;
    for (; k + 1 < r1; k += 2) {
        int e0 = eid[k], e1 = eid[k + 1];
        int s0 = col[k], s1 = col[k + 1];
        float4 xs0 = ld_half4(xq + (size_t)s0 * CC + q * 4);
        float4 xs1 = ld_half4(xq + (size_t)s1 * CC + q * 4);
        float p0 = 0.f, p1 = 0.f;
        if (e0 >= 0) {
            float4 ev = *(const float4*)(ea + (size_t)e0 * CC + q * 4);
            p0 = xs0.x * xd.x * ev.x + xs0.y * xd.y * ev.y +
                 xs0.z * xd.z * ev.z + xs0.w * xd.w * ev.w;
        }
        if (e1 >= 0) {
            float4 ev = *(const float4*)(ea + (size_t)e1 * CC + q * 4);
            p1 = xs1.x * xd.x * ev.x + xs1.y * xd.y * ev.y +
                 xs1.z * xd.z * ev.z + xs1.w * xd.w * ev.w;
        }
        #pragma unroll
        for (int off = 16; off; off >>= 1) {
            p0 += __shfl_xor(p0, off);
            p1 += __shfl_xor(p1, off);
        }
        if (q == 0) {
            if (e0 >= 0) score[e0] = 1.0f / (1.0f + __expf(-p0));
            if (e1 >= 0) score[e1] = 1.0f / (1.0f + __expf(-p1));
        }
    }
    if (k < r1) {
        int e0 = eid[k];
        if (e0 >= 0) {
            int s0 = col[k];
            float4 xs0 = ld_half4(xq + (size_t)s0 * CC + q * 4);
            float4 ev = *(const float4*)(ea + (size_t)e0 * CC + q * 4);
            float p0 = xs0.x * xd.x * ev.x + xs0.y * xd.y * ev.y +
                       xs0.z * xd.z * ev.z + xs0.w * xd.w * ev.w;
            #pragma unroll
            for (int off = 16; off; off >>= 1) p0 += __shfl_xor(p0, off);
            if (q == 0) score[e0] = 1.0f / (1.0f + __expf(-p0));
        }
    }
}

extern "C" void kernel_launch(void* const* d_in, const int* in_sizes, int n_in,
                              void* d_out, int out_size, void* d_ws, size_t ws_size,
                              hipStream_t stream) {
    (void)in_sizes; (void)n_in; (void)out_size; (void)ws_size;
    const float* x       = (const float*)d_in[0];
    const int*   eidx    = (const int*)d_in[1];
    const float* ea      = (const float*)d_in[2];
    const float* W1      = (const float*)d_in[3];
    const float* a_src1  = (const float*)d_in[4];
    const float* a_dst1  = (const float*)d_in[5];
    const float* b1      = (const float*)d_in[6];
    const float* W2      = (const float*)d_in[7];
    const float* a_src2  = (const float*)d_in[8];
    const float* a_dst2  = (const float*)d_in[9];
    const float* b2      = (const float*)d_in[10];

    const int* srcp = eidx;
    const int* dstp = eidx + EE;

    char* ws = (char*)d_ws;
    auto alloc = [&](size_t bytes) {
        char* p = ws;
        ws += (bytes + 255) & ~(size_t)255;
        return p;
    };
    const int NB = (NN + 255) / 256;   // 196
    int*    cnt     = (int*)alloc((size_t)NN * 4);
    int*    rowptr  = (int*)alloc((size_t)(NN + 1) * 4);
    int*    fillptr = (int*)alloc((size_t)NN * 4);
    int*    col     = (int*)alloc((size_t)(EE + NN) * 4);
    int*    eid     = (int*)alloc((size_t)(EE + NN) * 4);
    int*    bsum    = (int*)alloc((size_t)NB * 4);
    float*  a4      = (float*)alloc((size_t)NN * 4 * 4);
    __half* xp      = (__half*)alloc((size_t)NN * 256 * 2);
    float*  x1      = (float*)alloc((size_t)NN * CC * 4);
    __half* xq      = (__half*)alloc((size_t)NN * CC * 2);   // fp16 pre-act shadow

    float* outx = (float*)d_out;                 // [N, C]
    float* outs = outx + (size_t)NN * CC;        // [E]

    int total = EE + NN;

    // --- CSR build (shared by both layers) ---
    zero_kernel<<<(NN + 255) / 256, 256, 0, stream>>>(cnt, NN);
    count_kernel<<<(total + 255) / 256, 256, 0, stream>>>(dstp, cnt, EE, NN);
    bsum_kernel<<<NB, 256, 0, stream>>>(cnt, bsum, NN);
    bscan_kernel<<<1, 256, 0, stream>>>(bsum, NB);
    scan2_kernel<<<NB, 256, 0, stream>>>(cnt, bsum, rowptr, fillptr, NN);
    scatter_kernel<<<(total + 255) / 256, 256, 0, stream>>>(srcp, dstp, fillptr, col, eid, EE, NN);

    dim3 ggrid((NN + BM - 1) / BM, 2);

    // --- layer 1 (a4 fused into gemm epilogue; agg writes post-act) ---
    gemm_kernel<<<ggrid, 256, 0, stream>>>(x, W1, a_src1, a_dst1, xp, a4, NN);
    agg_kernel<<<NN / 8, 256, 0, stream>>>(xp, a4, rowptr, col, b1, x1, xq, 0);

    // --- layer 2 (x1 is already post-act; agg writes fp16 pre-act shadow too) ---
    gemm_kernel<<<ggrid, 256, 0, stream>>>(x1, W2, a_src2, a_dst2, xp, a4, NN);
    agg_kernel<<<NN / 8, 256, 0, stream>>>(xp, a4, rowptr, col, b2, outx, xq, 1);

    // --- score in CSR order (xq[dst] loaded once per node) ---
    score_kernel<<<NN / 8, 256, 0, stream>>>(xq, rowptr, col, eid, ea, outs);
}